// Round 1
// baseline (928.520 us; speedup 1.0000x reference)
//
#include <hip/hip_runtime.h>

#define DIM   128
#define DIM4  32          // DIM / 4 float4s per row
#define NGRAPH 4096
#define EPSV  1e-5f

// ---------------------------------------------------------------------------
// Pass 1: one block per graph. segment_ids is sorted, so each graph's nodes
// are contiguous: find [start,end) by binary search, accumulate sum & sumsq
// per dim in registers (float4), LDS-reduce, emit per-(g,d) affine params:
//   A = weight * rsqrt(var + eps),  B = bias - mean*mean_scale*A
// where var = E[x^2] - mean^2 * s * (2 - s)   (exact expansion, one pass)
// ---------------------------------------------------------------------------
__global__ __launch_bounds__(256) void gn_stats(
    const float* __restrict__ feat, const int* __restrict__ seg,
    const float* __restrict__ weight, const float* __restrict__ bias,
    const float* __restrict__ mscale,
    float* __restrict__ A, float* __restrict__ B, int N)
{
    const int g = blockIdx.x;

    // lower_bound(seg, g) and lower_bound(seg, g+1); all threads redundantly
    // (same addresses -> broadcast loads, ~20 iters each)
    int lo = 0, hi = N;
    while (lo < hi) { int mid = (lo + hi) >> 1; if (seg[mid] < g) lo = mid + 1; else hi = mid; }
    const int start = lo;
    hi = N;
    while (lo < hi) { int mid = (lo + hi) >> 1; if (seg[mid] < g + 1) lo = mid + 1; else hi = mid; }
    const int end = lo;

    const int tid  = threadIdx.x;
    const int dim4 = tid & 31;   // which float4 within the 128-dim row
    const int noff = tid >> 5;   // node slice 0..7

    float4 s = make_float4(0.f, 0.f, 0.f, 0.f);
    float4 q = make_float4(0.f, 0.f, 0.f, 0.f);
    for (int n = start + noff; n < end; n += 8) {
        const float4 x = ((const float4*)(feat + (size_t)n * DIM))[dim4];
        s.x += x.x; s.y += x.y; s.z += x.z; s.w += x.w;
        q.x += x.x * x.x; q.y += x.y * x.y; q.z += x.z * x.z; q.w += x.w * x.w;
    }

    __shared__ float4 ls[256];
    __shared__ float4 lq[256];
    ls[tid] = s; lq[tid] = q;
    __syncthreads();
    // reduce the 8 node slices (threads t, t+32, ..., t+224)
    for (int off = 128; off >= 32; off >>= 1) {
        if (tid < off) {
            float4 a = ls[tid], b = ls[tid + off];
            a.x += b.x; a.y += b.y; a.z += b.z; a.w += b.w; ls[tid] = a;
            float4 c = lq[tid], d = lq[tid + off];
            c.x += d.x; c.y += d.y; c.z += d.z; c.w += d.w; lq[tid] = c;
        }
        __syncthreads();
    }

    if (tid < 32) {
        const int   cnt   = (end - start) > 1 ? (end - start) : 1;
        const float inv_c = 1.0f / (float)cnt;
        const float4 S = ls[tid];
        const float4 Q = lq[tid];
#pragma unroll
        for (int j = 0; j < 4; ++j) {
            const int   d   = tid * 4 + j;
            const float Sv  = (&S.x)[j];
            const float Qv  = (&Q.x)[j];
            const float m   = Sv * inv_c;
            const float sc  = mscale[d];
            const float var = Qv * inv_c - m * m * sc * (2.0f - sc);
            const float inv = rsqrtf(var + EPSV);
            const float a   = weight[d] * inv;
            const float b   = bias[d] - m * sc * a;
            A[(size_t)g * DIM + d] = a;
            B[(size_t)g * DIM + d] = b;
        }
    }
}

// ---------------------------------------------------------------------------
// Pass 2: y = fma(x, A[seg,d], B[seg,d]); one float4 per thread.
// A/B total 4 MB -> L2/LLC resident; seg read is shared by 32 lanes.
// ---------------------------------------------------------------------------
__global__ __launch_bounds__(256) void gn_apply(
    const float* __restrict__ feat, const int* __restrict__ seg,
    const float* __restrict__ A, const float* __restrict__ B,
    float* __restrict__ out, int N)
{
    const size_t gid   = (size_t)blockIdx.x * 256 + threadIdx.x;
    const size_t total = (size_t)N * DIM4;
    if (gid >= total) return;
    const int node = (int)(gid >> 5);
    const int d4   = (int)(gid & 31);
    const int g    = seg[node];

    const float4 x = ((const float4*)feat)[gid];
    const float4 a = ((const float4*)A)[(size_t)g * DIM4 + d4];
    const float4 b = ((const float4*)B)[(size_t)g * DIM4 + d4];
    float4 r;
    r.x = fmaf(x.x, a.x, b.x);
    r.y = fmaf(x.y, a.y, b.y);
    r.z = fmaf(x.z, a.z, b.z);
    r.w = fmaf(x.w, a.w, b.w);
    ((float4*)out)[gid] = r;
}

extern "C" void kernel_launch(void* const* d_in, const int* in_sizes, int n_in,
                              void* d_out, int out_size, void* d_ws, size_t ws_size,
                              hipStream_t stream) {
    const float* feat   = (const float*)d_in[0];
    const int*   seg    = (const int*)d_in[1];
    // d_in[2] = num_graphs (device scalar) — shape is fixed, use NGRAPH
    const float* weight = (const float*)d_in[3];
    const float* bias   = (const float*)d_in[4];
    const float* mscale = (const float*)d_in[5];
    float*       out    = (float*)d_out;
    const int N = in_sizes[1];

    float* A = (float*)d_ws;                       // NGRAPH*DIM floats
    float* B = A + (size_t)NGRAPH * DIM;           // NGRAPH*DIM floats

    hipLaunchKernelGGL(gn_stats, dim3(NGRAPH), dim3(256), 0, stream,
                       feat, seg, weight, bias, mscale, A, B, N);

    const size_t total  = (size_t)N * DIM4;
    const int    blocks = (int)((total + 255) / 256);
    hipLaunchKernelGGL(gn_apply, dim3(blocks), dim3(256), 0, stream,
                       feat, seg, A, B, out, N);
}